// Round 1
// baseline (1119.904 us; speedup 1.0000x reference)
//
#include <hip/hip_runtime.h>
#include <math.h>

#define BB 8
#define NN 2000
#define FIN 128
#define HH 4
#define FO 64
#define CC 256  // HH*FO

// ---------------------------------------------------------------------------
// K1: h = x @ W.  rows = B*N = 16000, K = 128, cols = 256.
// Block = 256 threads handles 16 rows x 256 cols; x-tile staged in LDS.
// ---------------------------------------------------------------------------
__global__ __launch_bounds__(256) void k_gemm_xw(const float* __restrict__ x,
                                                 const float* __restrict__ W,
                                                 float* __restrict__ hfeat) {
    __shared__ float xs[16 * FIN];
    const int row0 = blockIdx.x * 16;
    const int t = threadIdx.x;
    for (int k = t; k < 16 * FIN; k += 256) xs[k] = x[row0 * FIN + k];
    __syncthreads();
    const int c = t;  // 256 cols, one per thread
    float acc[16];
#pragma unroll
    for (int r = 0; r < 16; ++r) acc[r] = 0.f;
#pragma unroll 4
    for (int k = 0; k < FIN; ++k) {
        float w = W[k * CC + c];
#pragma unroll
        for (int r = 0; r < 16; ++r) acc[r] += xs[r * FIN + k] * w;
    }
#pragma unroll
    for (int r = 0; r < 16; ++r) hfeat[(row0 + r) * CC + c] = acc[r];
}

// ---------------------------------------------------------------------------
// K2: e_src[b][h][n] = h[b,n,h,:]·a[h,:Fo],  e_dst = h·a[h,Fo:].
// One wave per (b,n,h); lane = feature index; butterfly reduce.
// ---------------------------------------------------------------------------
__global__ __launch_bounds__(256) void k_calc_e(const float* __restrict__ hfeat,
                                                const float* __restrict__ a,
                                                float* __restrict__ e_src,
                                                float* __restrict__ e_dst) {
    const int widx = blockIdx.x * 4 + (threadIdx.x >> 6);  // [0, B*N*H)
    const int lane = threadIdx.x & 63;
    const int b = widx / (NN * HH);
    const int rem = widx - b * (NN * HH);
    const int n = rem / HH;
    const int h = rem - n * HH;
    const float hv = hfeat[((b * NN + n) * HH + h) * FO + lane];
    float p1 = hv * a[h * 2 * FO + lane];
    float p2 = hv * a[h * 2 * FO + FO + lane];
#pragma unroll
    for (int off = 32; off > 0; off >>= 1) {
        p1 += __shfl_xor(p1, off);
        p2 += __shfl_xor(p2, off);
    }
    if (lane == 0) {
        e_src[(b * HH + h) * NN + n] = p1;
        e_dst[(b * HH + h) * NN + n] = p2;
    }
}

// ---------------------------------------------------------------------------
// K3: softmax stats.  Block per (b,i); wave per head; online max/sum over j.
// Writes m[b][h][i] and rl[b][h][i] = 1/l.
// ---------------------------------------------------------------------------
__global__ __launch_bounds__(256) void k_softmax_ml(const int* __restrict__ adj,
                                                    const float* __restrict__ e_src,
                                                    const float* __restrict__ e_dst,
                                                    float* __restrict__ mArr,
                                                    float* __restrict__ rlArr) {
    __shared__ int adjr[NN];
    const int bi = blockIdx.x;
    const int b = bi / NN, i = bi - b * NN;
    const int t = threadIdx.x;
    for (int k = t; k < NN; k += 256) adjr[k] = adj[i * NN + k];
    __syncthreads();
    const int h = t >> 6, lane = t & 63;
    const float* ed = e_dst + (b * HH + h) * NN;
    const float ei = e_src[(b * HH + h) * NN + i];
    float m = -INFINITY, l = 0.f;
    for (int j = lane; j < NN; j += 64) {
        if (adjr[j]) {
            float s = ei + ed[j];
            s = s > 0.f ? s : 0.2f * s;
            if (s > m) {
                l = l * __expf(m - s) + 1.f;  // exp(-inf)=0 on first hit
                m = s;
            } else {
                l += __expf(s - m);
            }
        }
    }
#pragma unroll
    for (int off = 32; off > 0; off >>= 1) {
        float mo = __shfl_xor(m, off);
        float lo = __shfl_xor(l, off);
        float mn = fmaxf(m, mo);
        float ln;
        if (mn == -INFINITY) ln = 0.f;  // both lanes empty
        else ln = l * __expf(m - mn) + lo * __expf(mo - mn);
        m = mn; l = ln;
    }
    if (lane == 0) {
        mArr[(b * HH + h) * NN + i] = m;
        rlArr[(b * HH + h) * NN + i] = 1.f / l;
    }
}

// ---------------------------------------------------------------------------
// K4 (launched LAST): alpha[b,i,j,h] write.  h is innermost (stride 1), so a
// thread computes all 4 heads of one (b,i,j) and stores one float4 (coalesced,
// 16B/lane).  512 MB HBM write -> memory-bound kernel.
// ---------------------------------------------------------------------------
__global__ __launch_bounds__(256) void k_alpha(const int* __restrict__ adj,
                                               const float* __restrict__ e_src,
                                               const float* __restrict__ e_dst,
                                               const float* __restrict__ mArr,
                                               const float* __restrict__ rlArr,
                                               float* __restrict__ alpha) {
    const int bi = blockIdx.x;
    const int b = bi / NN, i = bi - b * NN;
    const int t = threadIdx.x;
    float ei[HH], mm[HH], rr[HH];
#pragma unroll
    for (int h = 0; h < HH; ++h) {
        ei[h] = e_src[(b * HH + h) * NN + i];
        mm[h] = mArr[(b * HH + h) * NN + i];
        rr[h] = rlArr[(b * HH + h) * NN + i];
    }
    const float* ed = e_dst + b * HH * NN;
    float* arow = alpha + (size_t)(b * NN + i) * (NN * HH);
    for (int j = t; j < NN; j += 256) {
        const int av = adj[i * NN + j];
        float s0 = ei[0] + ed[0 * NN + j]; s0 = s0 > 0.f ? s0 : 0.2f * s0;
        float s1 = ei[1] + ed[1 * NN + j]; s1 = s1 > 0.f ? s1 : 0.2f * s1;
        float s2 = ei[2] + ed[2 * NN + j]; s2 = s2 > 0.f ? s2 : 0.2f * s2;
        float s3 = ei[3] + ed[3 * NN + j]; s3 = s3 > 0.f ? s3 : 0.2f * s3;
        float4 o;
        o.x = av ? __expf(s0 - mm[0]) * rr[0] : 0.f;
        o.y = av ? __expf(s1 - mm[1]) * rr[1] : 0.f;
        o.z = av ? __expf(s2 - mm[2]) * rr[2] : 0.f;
        o.w = av ? __expf(s3 - mm[3]) * rr[3] : 0.f;
        *(float4*)(arow + (size_t)j * HH) = o;
    }
}

// ---------------------------------------------------------------------------
// K5: per-head partial of out.  Block per (b, i-tile=64, h).  For each j-tile
// of 64: stage h-features in LDS, recompute alpha tile in LDS (cheap exp),
// then 64x64x64 fp32 FMA with 4x4 register micro-tiles.
// part[h][b,i,f] = sum_j alpha[b,i,j,h] * hfeat[b,j,h,f]
// ---------------------------------------------------------------------------
__global__ __launch_bounds__(256) void k_out_partial(const int* __restrict__ adj,
                                                     const float* __restrict__ hfeat,
                                                     const float* __restrict__ e_src,
                                                     const float* __restrict__ e_dst,
                                                     const float* __restrict__ mArr,
                                                     const float* __restrict__ rlArr,
                                                     float* __restrict__ part) {
    __shared__ float hfs[64 * 64];      // [jj][f]
    __shared__ float ps[64 * 65];       // [il][jj], +1 pad
    __shared__ float es_l[64], ml_l[64], rl_l[64];
    const int it = blockIdx.x, h = blockIdx.y, b = blockIdx.z;
    const int i0 = it * 64;
    const int t = threadIdx.x;
    if (t < 64) {
        const int i = i0 + t;
        if (i < NN) {
            es_l[t] = e_src[(b * HH + h) * NN + i];
            ml_l[t] = mArr[(b * HH + h) * NN + i];
            rl_l[t] = rlArr[(b * HH + h) * NN + i];
        } else {
            es_l[t] = 0.f; ml_l[t] = 0.f; rl_l[t] = 0.f;
        }
    }
    __syncthreads();
    const int tf = t & 15, ti = t >> 4;  // thread owns f in [tf*4,tf*4+4), rows i0+ti*4..+3
    float acc[4][4] = {{0.f}};
    const float* ed = e_dst + (b * HH + h) * NN;

    for (int j0 = 0; j0 < NN; j0 += 64) {
        // stage h-feature tile
        for (int k = t; k < 4096; k += 256) {
            const int jj = k >> 6, f = k & 63;
            const int j = j0 + jj;
            hfs[k] = (j < NN) ? hfeat[((b * NN + j) * HH + h) * FO + f] : 0.f;
        }
        // recompute alpha tile (jj fast -> adj reads coalesced)
        for (int k = t; k < 4096; k += 256) {
            const int il = k >> 6, jj = k & 63;
            const int i = i0 + il, j = j0 + jj;
            float v = 0.f;
            if (i < NN && j < NN && adj[i * NN + j] != 0) {
                float s = es_l[il] + ed[j];
                s = s > 0.f ? s : 0.2f * s;
                v = __expf(s - ml_l[il]) * rl_l[il];
            }
            ps[il * 65 + jj] = v;
        }
        __syncthreads();
#pragma unroll 4
        for (int jj = 0; jj < 64; ++jj) {
            const float4 hv = *(const float4*)(hfs + jj * 64 + tf * 4);
            const float p0 = ps[(ti * 4 + 0) * 65 + jj];
            const float p1 = ps[(ti * 4 + 1) * 65 + jj];
            const float p2 = ps[(ti * 4 + 2) * 65 + jj];
            const float p3 = ps[(ti * 4 + 3) * 65 + jj];
            acc[0][0] += p0 * hv.x; acc[0][1] += p0 * hv.y; acc[0][2] += p0 * hv.z; acc[0][3] += p0 * hv.w;
            acc[1][0] += p1 * hv.x; acc[1][1] += p1 * hv.y; acc[1][2] += p1 * hv.z; acc[1][3] += p1 * hv.w;
            acc[2][0] += p2 * hv.x; acc[2][1] += p2 * hv.y; acc[2][2] += p2 * hv.z; acc[2][3] += p2 * hv.w;
            acc[3][0] += p3 * hv.x; acc[3][1] += p3 * hv.y; acc[3][2] += p3 * hv.z; acc[3][3] += p3 * hv.w;
        }
        __syncthreads();
    }
    float* pp = part + (size_t)h * (BB * NN * FO);
#pragma unroll
    for (int r = 0; r < 4; ++r) {
        const int i = i0 + ti * 4 + r;
        if (i < NN) {
            float4 o = make_float4(acc[r][0], acc[r][1], acc[r][2], acc[r][3]);
            *(float4*)(pp + (size_t)(b * NN + i) * FO + tf * 4) = o;
        }
    }
}

// ---------------------------------------------------------------------------
// K6: out = 0.25 * sum_h part[h]
// ---------------------------------------------------------------------------
__global__ __launch_bounds__(256) void k_reduce(const float* __restrict__ part,
                                                float* __restrict__ out) {
    const int idx = blockIdx.x * 256 + threadIdx.x;
    const int M = BB * NN * FO;
    out[idx] = 0.25f * (part[idx] + part[M + idx] + part[2 * M + idx] + part[3 * M + idx]);
}

// ---------------------------------------------------------------------------
// Launch.  Scratch plan: big scratch (hfeat 16.4MB, part 16.4MB) lives at the
// START of the alpha output region — legal because k_alpha (which overwrites
// it) runs LAST on the stream.  d_ws only holds the 1MB of e/m/rl arrays.
// ---------------------------------------------------------------------------
extern "C" void kernel_launch(void* const* d_in, const int* in_sizes, int n_in,
                              void* d_out, int out_size, void* d_ws, size_t ws_size,
                              hipStream_t stream) {
    const float* x  = (const float*)d_in[0];
    const int* adj  = (const int*)d_in[1];
    const float* W  = (const float*)d_in[2];
    const float* a  = (const float*)d_in[3];

    float* out = (float*)d_out;                         // B*N*FO = 1,024,000 floats
    float* alpha = out + (size_t)BB * NN * FO;          // 128,000,000 floats

    // scratch inside alpha region (dead before k_alpha runs)
    float* hfeat = alpha;                               // 4,096,000 floats
    float* part  = alpha + (size_t)BB * NN * CC;        // 4,096,000 floats

    // small scratch in d_ws (needs 1,024,000 bytes)
    float* ws    = (float*)d_ws;
    float* e_src = ws;                                  // B*H*N = 64,000 each
    float* e_dst = e_src + BB * HH * NN;
    float* mArr  = e_dst + BB * HH * NN;
    float* rlArr = mArr + BB * HH * NN;

    k_gemm_xw<<<1000, 256, 0, stream>>>(x, W, hfeat);
    k_calc_e<<<16000, 256, 0, stream>>>(hfeat, a, e_src, e_dst);
    k_softmax_ml<<<16000, 256, 0, stream>>>(adj, e_src, e_dst, mArr, rlArr);
    k_out_partial<<<dim3(32, HH, BB), 256, 0, stream>>>(adj, hfeat, e_src, e_dst, mArr, rlArr, part);
    k_reduce<<<4000, 256, 0, stream>>>(part, out);
    k_alpha<<<16000, 256, 0, stream>>>(adj, e_src, e_dst, mArr, rlArr, alpha);  // overwrites scratch
}

// Round 2
// 1040.879 us; speedup vs baseline: 1.0759x; 1.0759x over previous
//
#include <hip/hip_runtime.h>
#include <math.h>

#define BB 8
#define NN 2000
#define FIN 128
#define HH 4
#define FO 64
#define CC 256  // HH*FO

typedef short bf16x8 __attribute__((ext_vector_type(8)));
typedef float f32x4 __attribute__((ext_vector_type(4)));

__device__ __forceinline__ unsigned short f2bf(float v) {
    union { float f; unsigned u; } x;
    x.f = v;
    unsigned r = x.u + 0x7fffu + ((x.u >> 16) & 1u);  // RNE
    return (unsigned short)(r >> 16);
}

// ---------------------------------------------------------------------------
// K1: h = x @ W.  rows = B*N = 16000, K = 128, cols = 256.
// float4 LDS reads (lane-uniform -> broadcast, conflict-free).
// ---------------------------------------------------------------------------
__global__ __launch_bounds__(256) void k_gemm_xw(const float* __restrict__ x,
                                                 const float* __restrict__ W,
                                                 float* __restrict__ hfeat) {
    __shared__ float xs[16 * FIN];
    const int row0 = blockIdx.x * 16;
    const int t = threadIdx.x;
    for (int k = t; k < 16 * FIN; k += 256) xs[k] = x[row0 * FIN + k];
    __syncthreads();
    const int c = t;
    float acc[16];
#pragma unroll
    for (int r = 0; r < 16; ++r) acc[r] = 0.f;
#pragma unroll 2
    for (int k = 0; k < FIN; k += 4) {
        const float w0 = W[(k + 0) * CC + c];
        const float w1 = W[(k + 1) * CC + c];
        const float w2 = W[(k + 2) * CC + c];
        const float w3 = W[(k + 3) * CC + c];
#pragma unroll
        for (int r = 0; r < 16; ++r) {
            const float4 xv = *(const float4*)(xs + r * FIN + k);
            acc[r] = fmaf(xv.x, w0, fmaf(xv.y, w1, fmaf(xv.z, w2, fmaf(xv.w, w3, acc[r]))));
        }
    }
#pragma unroll
    for (int r = 0; r < 16; ++r) hfeat[(row0 + r) * CC + c] = acc[r];
}

// ---------------------------------------------------------------------------
// K2: e_src[b][h][n] = h·a_src, e_dst = h·a_dst.  Wave per (b,n,h).
// ---------------------------------------------------------------------------
__global__ __launch_bounds__(256) void k_calc_e(const float* __restrict__ hfeat,
                                                const float* __restrict__ a,
                                                float* __restrict__ e_src,
                                                float* __restrict__ e_dst) {
    const int widx = blockIdx.x * 4 + (threadIdx.x >> 6);
    const int lane = threadIdx.x & 63;
    const int b = widx / (NN * HH);
    const int rem = widx - b * (NN * HH);
    const int n = rem / HH;
    const int h = rem - n * HH;
    const float hv = hfeat[((b * NN + n) * HH + h) * FO + lane];
    float p1 = hv * a[h * 2 * FO + lane];
    float p2 = hv * a[h * 2 * FO + FO + lane];
#pragma unroll
    for (int off = 32; off > 0; off >>= 1) {
        p1 += __shfl_xor(p1, off);
        p2 += __shfl_xor(p2, off);
    }
    if (lane == 0) {
        e_src[(b * HH + h) * NN + n] = p1;
        e_dst[(b * HH + h) * NN + n] = p2;
    }
}

// ---------------------------------------------------------------------------
// K3: softmax stats, branchless, no LDS, no barriers.  Wave per (b,i,h).
// Masked entries use -1e30 (finite): spurious l contributions get multiplied
// by exp(-1e30 - m_real) = 0 as soon as any real neighbor appears.
// ---------------------------------------------------------------------------
__global__ __launch_bounds__(256) void k_softmax_ml(const int* __restrict__ adj,
                                                    const float* __restrict__ e_src,
                                                    const float* __restrict__ e_dst,
                                                    float* __restrict__ mArr,
                                                    float* __restrict__ rlArr) {
    const int widx = blockIdx.x * 4 + (threadIdx.x >> 6);  // [0, B*N*H)
    const int lane = threadIdx.x & 63;
    const int b = widx / (NN * HH);
    const int rem = widx - b * (NN * HH);
    const int i = rem / HH;
    const int h = rem - i * HH;
    const float* ed = e_dst + (b * HH + h) * NN;
    const int* arow = adj + (size_t)i * NN;
    const float ei = e_src[(b * HH + h) * NN + i];
    float m = -1e30f, l = 0.f;
    for (int j = lane; j < NN; j += 64) {
        float s = ei + ed[j];
        s = s > 0.f ? s : 0.2f * s;
        s = arow[j] ? s : -1e30f;
        const float nm = fmaxf(m, s);
        l = l * __expf(m - nm) + __expf(s - nm);
        m = nm;
    }
#pragma unroll
    for (int off = 32; off > 0; off >>= 1) {
        const float mo = __shfl_xor(m, off);
        const float lo = __shfl_xor(l, off);
        const float mn = fmaxf(m, mo);
        l = l * __expf(m - mn) + lo * __expf(mo - mn);
        m = mn;
    }
    if (lane == 0) {
        mArr[(b * HH + h) * NN + i] = m;
        rlArr[(b * HH + h) * NN + i] = 1.f / l;
    }
}

// ---------------------------------------------------------------------------
// K4 (launched LAST): alpha[b,i,j,h] write, float4/thread, 512 MB HBM write.
// ---------------------------------------------------------------------------
__global__ __launch_bounds__(256) void k_alpha(const int* __restrict__ adj,
                                               const float* __restrict__ e_src,
                                               const float* __restrict__ e_dst,
                                               const float* __restrict__ mArr,
                                               const float* __restrict__ rlArr,
                                               float* __restrict__ alpha) {
    const int bi = blockIdx.x;
    const int b = bi / NN, i = bi - b * NN;
    const int t = threadIdx.x;
    float ei[HH], mm[HH], rr[HH];
#pragma unroll
    for (int h = 0; h < HH; ++h) {
        ei[h] = e_src[(b * HH + h) * NN + i];
        mm[h] = mArr[(b * HH + h) * NN + i];
        rr[h] = rlArr[(b * HH + h) * NN + i];
    }
    const float* ed = e_dst + b * HH * NN;
    float* arow = alpha + (size_t)(b * NN + i) * (NN * HH);
    for (int j = t; j < NN; j += 256) {
        const int av = adj[i * NN + j];
        float s0 = ei[0] + ed[0 * NN + j]; s0 = s0 > 0.f ? s0 : 0.2f * s0;
        float s1 = ei[1] + ed[1 * NN + j]; s1 = s1 > 0.f ? s1 : 0.2f * s1;
        float s2 = ei[2] + ed[2 * NN + j]; s2 = s2 > 0.f ? s2 : 0.2f * s2;
        float s3 = ei[3] + ed[3 * NN + j]; s3 = s3 > 0.f ? s3 : 0.2f * s3;
        float4 o;
        o.x = av ? __expf(s0 - mm[0]) * rr[0] : 0.f;
        o.y = av ? __expf(s1 - mm[1]) * rr[1] : 0.f;
        o.z = av ? __expf(s2 - mm[2]) * rr[2] : 0.f;
        o.w = av ? __expf(s3 - mm[3]) * rr[3] : 0.f;
        *(float4*)(arow + (size_t)j * HH) = o;
    }
}

// ---------------------------------------------------------------------------
// K5: per-head partial via bf16 MFMA.  Block per (i-tile=64, h, b).
// D = Ht · P^T :  A = Ht[f][j] (M=f, K=j), B = P[i][j] (N=i, K=j) — both
// operands j-contiguous in LDS (rows padded to 72 ushorts = 144B, 16B-aligned).
// mfma_f32_16x16x32_bf16:  A[m=lane&15][k=quad*8+j]  (one ds_read_b128),
//                          B[k=quad*8+j][n=lane&15]  (one ds_read_b128),
//                          C/D: row(m)=quad*4+reg, col(n)=lane&15.
// Wave w owns i-quarter w*16; loops 4 f-tiles; fp32 accumulate.
// ---------------------------------------------------------------------------
__global__ __launch_bounds__(256) void k_out_mfma(const int* __restrict__ adj,
                                                  const float* __restrict__ hfeat,
                                                  const float* __restrict__ e_src,
                                                  const float* __restrict__ e_dst,
                                                  const float* __restrict__ mArr,
                                                  const float* __restrict__ rlArr,
                                                  float* __restrict__ part) {
    __shared__ __align__(16) char sm[18432];
    unsigned short* Ht = (unsigned short*)sm;            // [64][72]  f-major
    unsigned short* Pt = (unsigned short*)(sm + 9216);   // [64][72]  i-major
    __shared__ float es_l[64], ml_l[64], rl_l[64];
    const int it = blockIdx.x, h = blockIdx.y, b = blockIdx.z;
    const int i0 = it * 64;
    const int t = threadIdx.x;
    if (t < 64) {
        const int i = i0 + t;
        const bool ok = (i < NN);
        es_l[t] = ok ? e_src[(b * HH + h) * NN + i] : 0.f;
        ml_l[t] = ok ? mArr[(b * HH + h) * NN + i] : 0.f;
        rl_l[t] = ok ? rlArr[(b * HH + h) * NN + i] : 0.f;
    }
    __syncthreads();
    const int wave = t >> 6, lane = t & 63;
    const int quad = lane >> 4, l16 = lane & 15;
    f32x4 acc[4];
#pragma unroll
    for (int ft = 0; ft < 4; ++ft) {
        acc[ft][0] = 0.f; acc[ft][1] = 0.f; acc[ft][2] = 0.f; acc[ft][3] = 0.f;
    }
    const float* ed = e_dst + (b * HH + h) * NN;

    for (int j0 = 0; j0 < NN; j0 += 64) {
        // stage Ht[f][jj] = bf16(hfeat[b, j0+jj, h, f])  (read coalesced by f)
        for (int k = t; k < 4096; k += 256) {
            const int jj = k >> 6, f = k & 63;
            const int j = j0 + jj;
            const float v = (j < NN) ? hfeat[((b * NN + j) * HH + h) * FO + f] : 0.f;
            Ht[f * 72 + jj] = f2bf(v);
        }
        // stage Pt[il][jj] = bf16(alpha) (contiguous row writes, conflict-free)
        for (int k = t; k < 4096; k += 256) {
            const int il = k >> 6, jj = k & 63;
            const int i = i0 + il, j = j0 + jj;
            float v = 0.f;
            if (i < NN && j < NN && adj[i * NN + j] != 0) {
                float s = es_l[il] + ed[j];
                s = s > 0.f ? s : 0.2f * s;
                v = __expf(s - ml_l[il]) * rl_l[il];
            }
            Pt[il * 72 + jj] = f2bf(v);
        }
        __syncthreads();
#pragma unroll
        for (int kk = 0; kk < 2; ++kk) {
            const int kof = kk * 32 + quad * 8;
            const bf16x8 bfrag = *(const bf16x8*)(Pt + (wave * 16 + l16) * 72 + kof);
#pragma unroll
            for (int ft = 0; ft < 4; ++ft) {
                const bf16x8 afrag = *(const bf16x8*)(Ht + (ft * 16 + l16) * 72 + kof);
                acc[ft] = __builtin_amdgcn_mfma_f32_16x16x32_bf16(afrag, bfrag, acc[ft], 0, 0, 0);
            }
        }
        __syncthreads();
    }
    // transpose D through LDS: Dt[i_local][f], rows padded to 68 floats (16B-aligned)
    float* Dt = (float*)sm;
#pragma unroll
    for (int ft = 0; ft < 4; ++ft)
#pragma unroll
        for (int r = 0; r < 4; ++r)
            Dt[(wave * 16 + l16) * 68 + ft * 16 + quad * 4 + r] = acc[ft][r];
    __syncthreads();
    float* pp = part + (size_t)h * (BB * NN * FO);
    for (int k = t; k < 1024; k += 256) {
        const int i = k >> 4, f4 = (k & 15) * 4;
        const int gi = i0 + i;
        if (gi < NN) {
            const float4 v = *(const float4*)(Dt + i * 68 + f4);
            *(float4*)(pp + (size_t)(b * NN + gi) * FO + f4) = v;
        }
    }
}

// ---------------------------------------------------------------------------
// K6: out = 0.25 * sum_h part[h]
// ---------------------------------------------------------------------------
__global__ __launch_bounds__(256) void k_reduce(const float* __restrict__ part,
                                                float* __restrict__ out) {
    const int idx = blockIdx.x * 256 + threadIdx.x;
    const int M = BB * NN * FO;
    out[idx] = 0.25f * (part[idx] + part[M + idx] + part[2 * M + idx] + part[3 * M + idx]);
}

// ---------------------------------------------------------------------------
// Launch.  Big scratch (hfeat, part) lives at the start of the alpha output
// region — dead until k_alpha, which runs LAST.  d_ws holds 1 MB of e/m/rl.
// ---------------------------------------------------------------------------
extern "C" void kernel_launch(void* const* d_in, const int* in_sizes, int n_in,
                              void* d_out, int out_size, void* d_ws, size_t ws_size,
                              hipStream_t stream) {
    const float* x  = (const float*)d_in[0];
    const int* adj  = (const int*)d_in[1];
    const float* W  = (const float*)d_in[2];
    const float* a  = (const float*)d_in[3];

    float* out = (float*)d_out;                         // B*N*FO floats
    float* alpha = out + (size_t)BB * NN * FO;          // B*N*N*H floats

    float* hfeat = alpha;                               // 4,096,000 floats (scratch)
    float* part  = alpha + (size_t)BB * NN * CC;        // 4,096,000 floats (scratch)

    float* ws    = (float*)d_ws;
    float* e_src = ws;
    float* e_dst = e_src + BB * HH * NN;
    float* mArr  = e_dst + BB * HH * NN;
    float* rlArr = mArr + BB * HH * NN;

    k_gemm_xw<<<1000, 256, 0, stream>>>(x, W, hfeat);
    k_calc_e<<<16000, 256, 0, stream>>>(hfeat, a, e_src, e_dst);
    k_softmax_ml<<<16000, 256, 0, stream>>>(adj, e_src, e_dst, mArr, rlArr);
    k_out_mfma<<<dim3(32, HH, BB), 256, 0, stream>>>(adj, hfeat, e_src, e_dst, mArr, rlArr, part);
    k_reduce<<<4000, 256, 0, stream>>>(part, out);
    k_alpha<<<16000, 256, 0, stream>>>(adj, e_src, e_dst, mArr, rlArr, alpha);  // overwrites scratch
}